// Round 4
// baseline (227.429 us; speedup 1.0000x reference)
//
#include <hip/hip_runtime.h>
#include <cstdint>
#include <cstddef>

#define B_   256
#define D_   2048
#define U_   2048
#define NTOT 8192    // 4*U
#define BN   32
#define BK   64
#define KC   2048    // K per ksplit (ksplit=2 over K=4096)
#define ITERS (KC / BK)   // 32

typedef _Float16 half8 __attribute__((ext_vector_type(8)));
typedef _Float16 half4 __attribute__((ext_vector_type(4)));
typedef float floatx16 __attribute__((ext_vector_type(16)));

// ---------------------------------------------------------------------------
// prep: [x|h] fp32 -> f16, chunk-major layout [chunk=k/8][row][8] so the GEMM
// reads each MFMA A-fragment as one lane-contiguous global_load_dwordx4.
// ---------------------------------------------------------------------------
__global__ __launch_bounds__(256) void prep_kernel(
    const float* __restrict__ x, const float* __restrict__ h,
    _Float16* __restrict__ Ahi)
{
    int gid   = blockIdx.x * 256 + threadIdx.x;   // 131072 total
    int chunk = gid >> 8;                         // 0..511
    int row   = gid & 255;                        // 0..255
    int col0  = chunk * 8;
    const float* src = (col0 < D_) ? (x + row * D_ + col0)
                                   : (h + row * U_ + (col0 - D_));
    float4 v0 = *(const float4*)(src);
    float4 v1 = *(const float4*)(src + 4);
    float v[8] = {v0.x, v0.y, v0.z, v0.w, v1.x, v1.y, v1.z, v1.w};
    half8 hi;
#pragma unroll
    for (int i = 0; i < 8; ++i) hi[i] = (_Float16)v[i];
    *(half8*)(Ahi + (chunk * 256 + row) * 8) = hi;
}

// ---------------------------------------------------------------------------
// GEMM v5: two independent barrier domains per CU.
// 512 threads (8 waves), wave-tile 32x32 (waves stack M: rows w*32..w*32+31),
// BM=256, BN=32, grid (256,2) = 512 blocks = 2 blocks/CU = 16 waves/CU.
// A: NOT in LDS — L2-resident f16, direct global->reg fragments (512B
//    coalesced per half-wave), register double-buffered one full K-step
//    ahead; completion enforced by OUR vmcnt(4), issued before the barrier
//    so the compiler cannot collapse the pipeline (unlike v3).
// B: reg-staged fp32 -> f16 -> swizzled LDS (2 x 4KB), 2-step prefetch lead,
//    read as swizzled ds_read_b128.  vmcnt never drains to 0 in the loop.
// ---------------------------------------------------------------------------
__global__ __launch_bounds__(512, 4) void gemm_kernel(
    const _Float16* __restrict__ Ahi,
    const float* __restrict__ Wz, const float* __restrict__ Wi,
    const float* __restrict__ Wf, const float* __restrict__ Wo,
    const float* __restrict__ Uz, const float* __restrict__ Ui,
    const float* __restrict__ Uf, const float* __restrict__ Uo,
    float* __restrict__ P)
{
    __shared__ __align__(16) _Float16 sB[2][BK * BN];   // 2 x 4 KB

    const int t    = threadIdx.x;
    const int w    = t >> 6;          // wave 0..7 -> rows w*32..w*32+31
    const int lane = t & 63;
    const int lg   = lane >> 5;
    const int lm   = lane & 31;

    const int nblk = blockIdx.x;      // 0..255
    const int ks   = blockIdx.y;      // 0..1
    const int n0   = nblk * BN;
    const int g    = n0 >> 11;        // gate 0..3
    const int c0   = n0 & (U_ - 1);

    const float* wsel[8] = {Wz, Wi, Wf, Wo, Uz, Ui, Uf, Uo};
    const float* Bm = wsel[ks * 4 + g];        // ks=0 -> W*, ks=1 -> U*

    // A fragment base: frag(kk,kin) at chunk = ks*256 + kk*8 + kin*2 + lg,
    // row = w*32 + lm; addr = (chunk*256 + row)*8 halfs. Chunk stride = 2048.
    const _Float16* Ag = Ahi +
        ((size_t)(ks * 256 + lg) * 256 + (size_t)(w * 32 + lm)) * 8;

    // B staging: thread covers col = t&31, k rows sk0..sk0+3 (4 coalesced
    // fp32 loads), cvt, one swizzled ds_write_b64 (8B).
    const int scol = t & 31;
    const int sk0  = (t >> 5) * 4;    // 0,4,...,60
    const float* Bg = Bm + (size_t)sk0 * U_ + c0 + scol;
    const int swb = scol * 128 + ((sk0 * 2) ^ ((scol & 7) << 4));
    const int bswz = (lm & 7) << 4;   // read-side swizzle

    floatx16 acc = {};
    half8 abA[4], abB[4];
    float rbA[4], rbB[4];

#define ISSUE_A(tt, ab)                                                       \
    {                                                                         \
        _Pragma("unroll")                                                     \
        for (int kin = 0; kin < 4; ++kin)                                     \
            ab[kin] = *(const half8*)(Ag +                                    \
                ((size_t)(tt) * 8 + kin * 2) * 2048);                         \
    }

#define ISSUE_B(tt, rb)                                                       \
    {                                                                         \
        _Pragma("unroll")                                                     \
        for (int j = 0; j < 4; ++j)                                           \
            rb[j] = Bg[((size_t)(tt) * 64 + j) * U_];                         \
    }

#define WRITE_B(rb, buf)                                                      \
    {                                                                         \
        half4 hv;                                                             \
        _Pragma("unroll")                                                     \
        for (int j = 0; j < 4; ++j) hv[j] = (_Float16)rb[j];                  \
        *(half4*)((char*)&sB[buf][0] + swb) = hv;                             \
    }

#define COMPUTE(ab, buf)                                                      \
    {                                                                         \
        const char* bB = (const char*)&sB[buf][0];                            \
        half8 bfr[4];                                                         \
        _Pragma("unroll")                                                     \
        for (int kin = 0; kin < 4; ++kin)                                     \
            bfr[kin] = *(const half8*)(bB + lm * 128 +                        \
                ((kin * 32 + lg * 16) ^ bswz));                               \
        __builtin_amdgcn_s_setprio(1);                                        \
        _Pragma("unroll")                                                     \
        for (int kin = 0; kin < 4; ++kin)                                     \
            acc = __builtin_amdgcn_mfma_f32_32x32x16_f16(ab[kin], bfr[kin],   \
                                                         acc, 0, 0, 0);       \
        __builtin_amdgcn_s_setprio(0);                                        \
    }

    // ---- prologue ----
    ISSUE_B(0, rbA);          // oldest 4 vmem
    ISSUE_A(0, abA);          // next 4
    ISSUE_B(1, rbB);          // next 4
    WRITE_B(rbA, 0);          // cvt rbA -> compiler waits vmcnt(8)
    asm volatile("s_waitcnt vmcnt(4) lgkmcnt(0)" ::: "memory");  // A(0) done
    __builtin_amdgcn_s_barrier();

    // ---- main loop: steps t, t+1 per pass (static reg indices) ----
    for (int tt = 0; tt < ITERS - 2; tt += 2) {
        // even step tt: compute abA / sB[0]
        ISSUE_A(tt + 1, abB);
        ISSUE_B(tt + 2, rbA);
        COMPUTE(abA, 0);
        WRITE_B(rbB, 1);      // B(tt+1); compiler waits vmcnt(8)
        asm volatile("s_waitcnt vmcnt(4) lgkmcnt(0)" ::: "memory");  // A(tt+1)
        __builtin_amdgcn_s_barrier();

        // odd step tt+1: compute abB / sB[1]
        ISSUE_A(tt + 2, abA);
        ISSUE_B(tt + 3, rbB);
        COMPUTE(abB, 1);
        WRITE_B(rbA, 0);      // B(tt+2)
        asm volatile("s_waitcnt vmcnt(4) lgkmcnt(0)" ::: "memory");  // A(tt+2)
        __builtin_amdgcn_s_barrier();
    }

    // ---- epilogue: step ITERS-2 (even, abA / sB[0]) ----
    ISSUE_A(ITERS - 1, abB);
    COMPUTE(abA, 0);
    WRITE_B(rbB, 1);          // B(ITERS-1)
    asm volatile("s_waitcnt vmcnt(0) lgkmcnt(0)" ::: "memory");
    __builtin_amdgcn_s_barrier();
    // step ITERS-1 (odd, abB / sB[1])
    COMPUTE(abB, 1);

#undef ISSUE_A
#undef ISSUE_B
#undef WRITE_B
#undef COMPUTE

    // C/D layout: col=lane&31, row=(r&3)+8*(r>>2)+4*(lane>>5)
    float* Pks = P + (size_t)ks * ((size_t)B_ * NTOT);
#pragma unroll
    for (int r = 0; r < 16; ++r) {
        int m = w * 32 + 4 * lg + (r & 3) + 8 * (r >> 2);
        Pks[(size_t)m * NTOT + n0 + lm] = acc[r];
    }
}

// ---------------------------------------------------------------------------
// gates: reduce 2 partials, add bias, sLSTM exponential-gate math,
// out = stack([h_t, c_t, n_t, m_t])
// ---------------------------------------------------------------------------
__global__ __launch_bounds__(256) void gates_kernel(
    const float* __restrict__ P,
    const float* __restrict__ c_prev, const float* __restrict__ n_prev,
    const float* __restrict__ m_prev,
    const float* __restrict__ bz, const float* __restrict__ bi,
    const float* __restrict__ bf, const float* __restrict__ bo,
    float* __restrict__ out)
{
    const size_t PS = (size_t)B_ * NTOT;
    const int OS = B_ * U_;
    int gid = blockIdx.x * 256 + threadIdx.x;   // 131072
    int m = gid >> 9;
    int u = (gid & 511) * 4;

    float pre[4][4];
#pragma unroll
    for (int gi = 0; gi < 4; ++gi) {
        const float* base = P + (size_t)m * NTOT + gi * U_ + u;
        float4 s0 = *(const float4*)(base);
        float4 s1 = *(const float4*)(base + PS);
        pre[gi][0] = s0.x + s1.x;
        pre[gi][1] = s0.y + s1.y;
        pre[gi][2] = s0.z + s1.z;
        pre[gi][3] = s0.w + s1.w;
    }
    float4 bzv = *(const float4*)(bz + u);
    float4 biv = *(const float4*)(bi + u);
    float4 bfv = *(const float4*)(bf + u);
    float4 bov = *(const float4*)(bo + u);
    float bza[4] = {bzv.x, bzv.y, bzv.z, bzv.w};
    float bia[4] = {biv.x, biv.y, biv.z, biv.w};
    float bfa[4] = {bfv.x, bfv.y, bfv.z, bfv.w};
    float boa[4] = {bov.x, bov.y, bov.z, bov.w};

    float4 cp4 = *(const float4*)(c_prev + m * U_ + u);
    float4 np4 = *(const float4*)(n_prev + m * U_ + u);
    float4 mp4 = *(const float4*)(m_prev + m * U_ + u);
    float cpa[4] = {cp4.x, cp4.y, cp4.z, cp4.w};
    float npa[4] = {np4.x, np4.y, np4.z, np4.w};
    float mpa[4] = {mp4.x, mp4.y, mp4.z, mp4.w};

    float hr[4], cr[4], nr[4], mr[4];
#pragma unroll
    for (int e = 0; e < 4; ++e) {
        float zt = pre[0][e] + bza[e];
        float it = pre[1][e] + bia[e];
        float ft = pre[2][e] + bfa[e];
        float ot = pre[3][e] + boa[e];
        float mp = mpa[e];
        float m_t = fmaxf(it + mp, it);
        float i_t = expf(it - m_t);
        float f_t = expf(ft + mp - m_t);
        float o_t = 1.0f / (1.0f + expf(-ot));
        float z_t = tanhf(zt);
        float c_t = f_t * cpa[e] + i_t * z_t;
        float n_t = f_t * npa[e] + i_t;
        float h_t = o_t * (c_t / (n_t + 1e-8f));
        hr[e] = h_t; cr[e] = c_t; nr[e] = n_t; mr[e] = m_t;
    }
    float4 hv = {hr[0], hr[1], hr[2], hr[3]};
    float4 cv = {cr[0], cr[1], cr[2], cr[3]};
    float4 nv = {nr[0], nr[1], nr[2], nr[3]};
    float4 mv = {mr[0], mr[1], mr[2], mr[3]};
    *(float4*)(out + 0 * OS + m * U_ + u) = hv;
    *(float4*)(out + 1 * OS + m * U_ + u) = cv;
    *(float4*)(out + 2 * OS + m * U_ + u) = nv;
    *(float4*)(out + 3 * OS + m * U_ + u) = mv;
}

extern "C" void kernel_launch(void* const* d_in, const int* in_sizes, int n_in,
                              void* d_out, int out_size, void* d_ws, size_t ws_size,
                              hipStream_t stream)
{
    const float* x  = (const float*)d_in[0];
    const float* h  = (const float*)d_in[1];
    const float* cp = (const float*)d_in[2];
    const float* np = (const float*)d_in[3];
    const float* mp = (const float*)d_in[4];
    const float* Wz = (const float*)d_in[5];
    const float* Wi = (const float*)d_in[6];
    const float* Wf = (const float*)d_in[7];
    const float* Wo = (const float*)d_in[8];
    const float* bz = (const float*)d_in[9];
    const float* bi = (const float*)d_in[10];
    const float* bf = (const float*)d_in[11];
    const float* bo = (const float*)d_in[12];
    const float* Uz = (const float*)d_in[13];
    const float* Ui = (const float*)d_in[14];
    const float* Uf = (const float*)d_in[15];
    const float* Uo = (const float*)d_in[16];

    float* P = (float*)d_ws;                         // 2*256*8192 f32 = 16.8 MB
    _Float16* Ahi = (_Float16*)((char*)d_ws + (size_t)2 * B_ * NTOT * sizeof(float));

    prep_kernel<<<512, 256, 0, stream>>>(x, h, Ahi);
    gemm_kernel<<<dim3(256, 2), 512, 0, stream>>>(Ahi,
        Wz, Wi, Wf, Wo, Uz, Ui, Uf, Uo, P);
    gates_kernel<<<512, 256, 0, stream>>>(P, cp, np, mp, bz, bi, bf, bo,
        (float*)d_out);
}

// Round 5
// 213.146 us; speedup vs baseline: 1.0670x; 1.0670x over previous
//
#include <hip/hip_runtime.h>
#include <cstdint>
#include <cstddef>

#define B_   256
#define D_   2048
#define U_   2048
#define NTOT 8192    // 4*U
#define BN   32
#define BK   64
#define KC   2048    // K per ksplit (ksplit=2 over K=4096)
#define ITERS (KC / BK)   // 32

typedef _Float16 half8 __attribute__((ext_vector_type(8)));
typedef float floatx16 __attribute__((ext_vector_type(16)));

// ---------------------------------------------------------------------------
// prep: [x|h] fp32 -> f16, chunk-major layout [chunk=k/8][row][8] so the GEMM
// stages A with contiguous global_load_lds and reads fragments as ds_read_b128.
// ---------------------------------------------------------------------------
__global__ __launch_bounds__(256) void prep_kernel(
    const float* __restrict__ x, const float* __restrict__ h,
    _Float16* __restrict__ Ahi)
{
    int gid   = blockIdx.x * 256 + threadIdx.x;   // 131072 total
    int chunk = gid >> 8;                         // 0..511
    int row   = gid & 255;                        // 0..255
    int col0  = chunk * 8;
    const float* src = (col0 < D_) ? (x + row * D_ + col0)
                                   : (h + row * U_ + (col0 - D_));
    float4 v0 = *(const float4*)(src);
    float4 v1 = *(const float4*)(src + 4);
    float v[8] = {v0.x, v0.y, v0.z, v0.w, v1.x, v1.y, v1.z, v1.w};
    half8 hi;
#pragma unroll
    for (int i = 0; i < 8; ++i) hi[i] = (_Float16)v[i];
    *(half8*)(Ahi + (chunk * 256 + row) * 8) = hi;
}

// ---------------------------------------------------------------------------
// GEMM v6: v4's proven pipeline at HALF block size -> 2 independent barrier
// domains per CU.  256 threads (4 waves), wave-tile 64x32 (waves stack M),
// BM=256, BN=32, grid (256,2) = 512 blocks = 2 blocks/CU.
// A: f16 chunk-major via global_load_lds (8 x 16B per thread), LDS dbuf.
// B: reg-staged fp32 -> f16 -> swizzled ds_write_b128, 2-step prefetch lead.
// Per step: issue A(t+1) -> issue B(t+2) -> compute t -> cvt+write B(t+1)
// -> s_waitcnt vmcnt(8) (A(t+1) done, B(t+2) stays in flight across the
// barrier) -> s_barrier.  vmcnt never drains to 0 in the main loop.
// LDS = 68 KB -> exactly 2 blocks/CU; when one block drains its barrier,
// the other block's waves keep the MFMA/LDS/VMEM pipes fed.
// ---------------------------------------------------------------------------
__global__ __launch_bounds__(256, 2) void gemm_kernel(
    const _Float16* __restrict__ Ahi,
    const float* __restrict__ Wz, const float* __restrict__ Wi,
    const float* __restrict__ Wf, const float* __restrict__ Wo,
    const float* __restrict__ Uz, const float* __restrict__ Ui,
    const float* __restrict__ Uf, const float* __restrict__ Uo,
    float* __restrict__ P)
{
    __shared__ __align__(16) _Float16 sA[2][8 * 256 * 8];   // 2 x 32 KB
    __shared__ __align__(16) _Float16 sB[2][BK * BN];       // 2 x 4 KB

    const int t    = threadIdx.x;
    const int w    = t >> 6;          // wave 0..3 -> rows w*64..w*64+63
    const int lane = t & 63;
    const int lg   = lane >> 5;
    const int lm   = lane & 31;

    const int nblk = blockIdx.x;      // 0..255
    const int ks   = blockIdx.y;      // 0..1
    const int n0   = nblk * BN;
    const int g    = n0 >> 11;        // gate 0..3
    const int c0   = n0 & (U_ - 1);

    const float* wsel[8] = {Wz, Wi, Wf, Wo, Uz, Ui, Uf, Uo};
    const float* Bm = wsel[ks * 4 + g];        // ks=0 -> W*, ks=1 -> U*
    const int chunk0 = ks * 256;               // A chunk base (chunk = k/8)

    // --- A staging: 8 global_load_lds per thread, linear flat copy.
    //     flat half idx within K-tile: (w*8+i)*512 + lane*8, i = 0..7.
    const _Float16* Ag = Ahi + (size_t)chunk0 * 2048
                             + (size_t)(w * 8) * 512 + (size_t)lane * 8;

    // --- B staging: thread covers col = t&31, k rows sk0..sk0+7
    //     (8 coalesced fp32 loads), cvt, one swizzled ds_write_b128.
    const int scol = t & 31;
    const int sk0  = (t >> 5) * 8;    // 0,8,...,56
    const float* Bg = Bm + (size_t)sk0 * U_ + c0 + scol;
    const int swb = scol * 128 + ((sk0 * 2) ^ ((scol & 7) << 4));
    const int bswz = (lm & 7) << 4;   // read-side swizzle

    // --- compute-phase A fragment byte offset (per kin add 8192, a1 +512)
    const int aoff = lg * 4096 + (w * 64 + lm) * 16;

    floatx16 acc0 = {}, acc1 = {};
    float rbA[8], rbB[8];

#define ISSUE_A(tt, buf)                                                      \
    {                                                                         \
        _Pragma("unroll")                                                     \
        for (int i = 0; i < 8; ++i)                                           \
            __builtin_amdgcn_global_load_lds(                                 \
                (const __attribute__((address_space(1))) void*)(              \
                    Ag + (size_t)(tt) * 16384 + i * 512),                     \
                (__attribute__((address_space(3))) void*)(                    \
                    (char*)&sA[buf][0] + (w * 8 + i) * 1024 + lane * 16),     \
                16, 0, 0);                                                    \
    }

#define ISSUE_B(tt, rb)                                                       \
    {                                                                         \
        _Pragma("unroll")                                                     \
        for (int j = 0; j < 8; ++j)                                           \
            rb[j] = Bg[((size_t)(tt) * 64 + j) * U_];                         \
    }

#define WRITE_B(rb, buf)                                                      \
    {                                                                         \
        half8 hv;                                                             \
        _Pragma("unroll")                                                     \
        for (int j = 0; j < 8; ++j) hv[j] = (_Float16)rb[j];                  \
        *(half8*)((char*)&sB[buf][0] + swb) = hv;                             \
    }

#define COMPUTE(cur)                                                          \
    {                                                                         \
        const char* bA = (const char*)&sA[cur][0];                            \
        const char* bB = (const char*)&sB[cur][0];                            \
        half8 af0[4], af1[4], bfr[4];                                         \
        _Pragma("unroll")                                                     \
        for (int kin = 0; kin < 4; ++kin) {                                   \
            af0[kin] = *(const half8*)(bA + aoff + kin * 8192);               \
            af1[kin] = *(const half8*)(bA + aoff + kin * 8192 + 512);         \
            bfr[kin] = *(const half8*)(bB + lm * 128 +                        \
                ((kin * 32 + lg * 16) ^ bswz));                               \
        }                                                                     \
        __builtin_amdgcn_s_setprio(1);                                        \
        _Pragma("unroll")                                                     \
        for (int kin = 0; kin < 4; ++kin) {                                   \
            acc0 = __builtin_amdgcn_mfma_f32_32x32x16_f16(af0[kin], bfr[kin], acc0, 0, 0, 0); \
            acc1 = __builtin_amdgcn_mfma_f32_32x32x16_f16(af1[kin], bfr[kin], acc1, 0, 0, 0); \
        }                                                                     \
        __builtin_amdgcn_s_setprio(0);                                        \
    }

    // ---- prologue: B(0)->rbA; A(0)->buf0; B(1)->rbB stays in flight
    ISSUE_B(0, rbA);
    ISSUE_A(0, 0);
    ISSUE_B(1, rbB);
    WRITE_B(rbA, 0);   // compiler inserts counted vmcnt(16) for rbA here
    asm volatile("s_waitcnt vmcnt(8) lgkmcnt(0)" ::: "memory");  // A(0) done
    __builtin_amdgcn_s_barrier();

    // ---- main loop: steps t, t+1 per pass (static reg indices)
    for (int tt = 0; tt < ITERS - 2; tt += 2) {
        // even step tt: compute buf0
        ISSUE_A(tt + 1, 1);
        ISSUE_B(tt + 2, rbA);
        COMPUTE(0);
        WRITE_B(rbB, 1);      // B(tt+1); compiler waits vmcnt(16)
        asm volatile("s_waitcnt vmcnt(8) lgkmcnt(0)" ::: "memory");  // A(tt+1)
        __builtin_amdgcn_s_barrier();

        // odd step tt+1: compute buf1
        ISSUE_A(tt + 2, 0);
        ISSUE_B(tt + 3, rbB);
        COMPUTE(1);
        WRITE_B(rbA, 0);      // B(tt+2)
        asm volatile("s_waitcnt vmcnt(8) lgkmcnt(0)" ::: "memory");  // A(tt+2)
        __builtin_amdgcn_s_barrier();
    }

    // ---- epilogue: step ITERS-2 (even, buf0), no B(ITERS) exists
    ISSUE_A(ITERS - 1, 1);
    COMPUTE(0);
    WRITE_B(rbB, 1);          // B(ITERS-1)
    asm volatile("s_waitcnt vmcnt(0) lgkmcnt(0)" ::: "memory");
    __builtin_amdgcn_s_barrier();
    // step ITERS-1 (odd, buf1)
    COMPUTE(1);

#undef ISSUE_A
#undef ISSUE_B
#undef WRITE_B
#undef COMPUTE

    // C/D layout: col=lane&31, row=(r&3)+8*(r>>2)+4*(lane>>5)
    float* Pks = P + (size_t)ks * ((size_t)B_ * NTOT);
#pragma unroll
    for (int r = 0; r < 16; ++r) {
        int m = w * 64 + 4 * lg + (r & 3) + 8 * (r >> 2);
        Pks[(size_t)m * NTOT + n0 + lm] = acc0[r];
    }
#pragma unroll
    for (int r = 0; r < 16; ++r) {
        int m = w * 64 + 32 + 4 * lg + (r & 3) + 8 * (r >> 2);
        Pks[(size_t)m * NTOT + n0 + lm] = acc1[r];
    }
}

// ---------------------------------------------------------------------------
// gates: reduce 2 partials, add bias, sLSTM exponential-gate math,
// out = stack([h_t, c_t, n_t, m_t])
// ---------------------------------------------------------------------------
__global__ __launch_bounds__(256) void gates_kernel(
    const float* __restrict__ P,
    const float* __restrict__ c_prev, const float* __restrict__ n_prev,
    const float* __restrict__ m_prev,
    const float* __restrict__ bz, const float* __restrict__ bi,
    const float* __restrict__ bf, const float* __restrict__ bo,
    float* __restrict__ out)
{
    const size_t PS = (size_t)B_ * NTOT;
    const int OS = B_ * U_;
    int gid = blockIdx.x * 256 + threadIdx.x;   // 131072
    int m = gid >> 9;
    int u = (gid & 511) * 4;

    float pre[4][4];
#pragma unroll
    for (int gi = 0; gi < 4; ++gi) {
        const float* base = P + (size_t)m * NTOT + gi * U_ + u;
        float4 s0 = *(const float4*)(base);
        float4 s1 = *(const float4*)(base + PS);
        pre[gi][0] = s0.x + s1.x;
        pre[gi][1] = s0.y + s1.y;
        pre[gi][2] = s0.z + s1.z;
        pre[gi][3] = s0.w + s1.w;
    }
    float4 bzv = *(const float4*)(bz + u);
    float4 biv = *(const float4*)(bi + u);
    float4 bfv = *(const float4*)(bf + u);
    float4 bov = *(const float4*)(bo + u);
    float bza[4] = {bzv.x, bzv.y, bzv.z, bzv.w};
    float bia[4] = {biv.x, biv.y, biv.z, biv.w};
    float bfa[4] = {bfv.x, bfv.y, bfv.z, bfv.w};
    float boa[4] = {bov.x, bov.y, bov.z, bov.w};

    float4 cp4 = *(const float4*)(c_prev + m * U_ + u);
    float4 np4 = *(const float4*)(n_prev + m * U_ + u);
    float4 mp4 = *(const float4*)(m_prev + m * U_ + u);
    float cpa[4] = {cp4.x, cp4.y, cp4.z, cp4.w};
    float npa[4] = {np4.x, np4.y, np4.z, np4.w};
    float mpa[4] = {mp4.x, mp4.y, mp4.z, mp4.w};

    float hr[4], cr[4], nr[4], mr[4];
#pragma unroll
    for (int e = 0; e < 4; ++e) {
        float zt = pre[0][e] + bza[e];
        float it = pre[1][e] + bia[e];
        float ft = pre[2][e] + bfa[e];
        float ot = pre[3][e] + boa[e];
        float mp = mpa[e];
        float m_t = fmaxf(it + mp, it);
        float i_t = expf(it - m_t);
        float f_t = expf(ft + mp - m_t);
        float o_t = 1.0f / (1.0f + expf(-ot));
        float z_t = tanhf(zt);
        float c_t = f_t * cpa[e] + i_t * z_t;
        float n_t = f_t * npa[e] + i_t;
        float h_t = o_t * (c_t / (n_t + 1e-8f));
        hr[e] = h_t; cr[e] = c_t; nr[e] = n_t; mr[e] = m_t;
    }
    float4 hv = {hr[0], hr[1], hr[2], hr[3]};
    float4 cv = {cr[0], cr[1], cr[2], cr[3]};
    float4 nv = {nr[0], nr[1], nr[2], nr[3]};
    float4 mv = {mr[0], mr[1], mr[2], mr[3]};
    *(float4*)(out + 0 * OS + m * U_ + u) = hv;
    *(float4*)(out + 1 * OS + m * U_ + u) = cv;
    *(float4*)(out + 2 * OS + m * U_ + u) = nv;
    *(float4*)(out + 3 * OS + m * U_ + u) = mv;
}

extern "C" void kernel_launch(void* const* d_in, const int* in_sizes, int n_in,
                              void* d_out, int out_size, void* d_ws, size_t ws_size,
                              hipStream_t stream)
{
    const float* x  = (const float*)d_in[0];
    const float* h  = (const float*)d_in[1];
    const float* cp = (const float*)d_in[2];
    const float* np = (const float*)d_in[3];
    const float* mp = (const float*)d_in[4];
    const float* Wz = (const float*)d_in[5];
    const float* Wi = (const float*)d_in[6];
    const float* Wf = (const float*)d_in[7];
    const float* Wo = (const float*)d_in[8];
    const float* bz = (const float*)d_in[9];
    const float* bi = (const float*)d_in[10];
    const float* bf = (const float*)d_in[11];
    const float* bo = (const float*)d_in[12];
    const float* Uz = (const float*)d_in[13];
    const float* Ui = (const float*)d_in[14];
    const float* Uf = (const float*)d_in[15];
    const float* Uo = (const float*)d_in[16];

    float* P = (float*)d_ws;                         // 2*256*8192 f32 = 16.8 MB
    _Float16* Ahi = (_Float16*)((char*)d_ws + (size_t)2 * B_ * NTOT * sizeof(float));

    prep_kernel<<<512, 256, 0, stream>>>(x, h, Ahi);
    gemm_kernel<<<dim3(256, 2), 256, 0, stream>>>(Ahi,
        Wz, Wi, Wf, Wo, Uz, Ui, Uf, Uo, P);
    gates_kernel<<<512, 256, 0, stream>>>(P, cp, np, mp, bz, bi, bf, bo,
        (float*)d_out);
}